// Round 1
// baseline (60.893 us; speedup 1.0000x reference)
//
#include <hip/hip_runtime.h>
#include <math.h>

#define T_LEN 2048
#define S_N   128
#define M_N   8
#define D_N   64
#define TBLK  8            // 2048 / 256 t-blocks per state
#define LOG2PI 1.8378770664093453f

// ---------------- prep over (s,m): fold log_norm + const term ---------------
// off[s*M+m] = -0.5*(sum_d log_vars + D*log(2pi)) - 0.5*sum_d mu^2*exp(-lv)
__global__ void prep_sm_kernel(const float* __restrict__ log_vars,
                               const float* __restrict__ means,
                               float* __restrict__ off) {
    int wave = threadIdx.x >> 6;          // 4 waves per block
    int lane = threadIdx.x & 63;          // = d
    int sm = blockIdx.x * 4 + wave;       // 0..1023
    float lv = log_vars[sm * 64 + lane];
    float mu = means[sm * 64 + lane];
    float iv = expf(-lv);
    float a = lv;
    float b = mu * mu * iv;
    #pragma unroll
    for (int o = 32; o > 0; o >>= 1) {
        a += __shfl_down(a, o, 64);
        b += __shfl_down(b, o, 64);
    }
    if (lane == 0)
        off[sm] = -0.5f * (a + 64.0f * LOG2PI) - 0.5f * b;
}

// ---------------- prep over s: log_mix_w, log_pi, C[s] ----------------------
__global__ void prep_s_kernel(const float* __restrict__ pi_logits,
                              const float* __restrict__ trans_logits,
                              const float* __restrict__ weight_logits,
                              float* __restrict__ off,     // [S*M] += logw
                              float* __restrict__ base) {  // [S]
    int s = threadIdx.x;                  // 128 threads
    // log_softmax of weight_logits row (M=8)
    float w[8];
    float mx = -INFINITY;
    #pragma unroll
    for (int m = 0; m < 8; m++) { w[m] = weight_logits[s * 8 + m]; mx = fmaxf(mx, w[m]); }
    float sum = 0.f;
    #pragma unroll
    for (int m = 0; m < 8; m++) sum += expf(w[m] - mx);
    float lse = mx + logf(sum);
    #pragma unroll
    for (int m = 0; m < 8; m++) off[s * 8 + m] += (w[m] - lse);

    // log_pi[s]
    float pmx = -INFINITY;
    for (int j = 0; j < 128; j++) pmx = fmaxf(pmx, pi_logits[j]);
    float psum = 0.f;
    for (int j = 0; j < 128; j++) psum += expf(pi_logits[j] - pmx);
    float log_pi = pi_logits[s] - (pmx + logf(psum));

    // C[s] = logsumexp_j(log_A[s,j]), log_A = trans - lse_row  (≈0, keep faithful)
    const float* tr = trans_logits + s * 128;
    float tmx = -INFINITY;
    for (int j = 0; j < 128; j++) tmx = fmaxf(tmx, tr[j]);
    float tsum = 0.f;
    for (int j = 0; j < 128; j++) tsum += expf(tr[j] - tmx);
    float L = tmx + logf(tsum);
    float cmx = tmx - L;
    float csum = 0.f;
    for (int j = 0; j < 128; j++) csum += expf((tr[j] - L) - cmx);
    float C = cmx + logf(csum);

    base[s] = log_pi + 2047.0f * C;       // (T-1)*C
}

// ---------------- main: emission log-probs + per-block t-sum ----------------
__global__ __launch_bounds__(256) void emis_kernel(
    const float* __restrict__ X,
    const float* __restrict__ means,
    const float* __restrict__ log_vars,
    const float* __restrict__ off,
    float* __restrict__ part) {            // [S*TBLK]
    __shared__ __align__(16) float siv[512];   // iv[s][m][d]
    __shared__ __align__(16) float sbiv[512];  // -2*mu*iv
    __shared__ float soff[8];
    __shared__ float red[4];

    int s  = blockIdx.x >> 3;
    int tb = blockIdx.x & 7;
    int tid = threadIdx.x;

    // stage params for this state
    for (int i = tid; i < 512; i += 256) {
        float lv = log_vars[s * 512 + i];
        float mu = means[s * 512 + i];
        float iv = expf(-lv);
        siv[i]  = iv;
        sbiv[i] = -2.0f * mu * iv;
    }
    if (tid < 8) soff[tid] = off[s * 8 + tid];
    __syncthreads();

    int t = tb * 256 + tid;
    const float4* Xv    = (const float4*)(X + (size_t)t * 64);
    const float4* siv4  = (const float4*)siv;
    const float4* sbiv4 = (const float4*)sbiv;

    float acc[8];
    #pragma unroll
    for (int m = 0; m < 8; m++) acc[m] = 0.f;

    #pragma unroll
    for (int c = 0; c < 2; c++) {         // two 32-wide d-chunks
        float4 xr[8], x2[8];
        #pragma unroll
        for (int j = 0; j < 8; j++) {
            xr[j] = Xv[c * 8 + j];
            x2[j].x = xr[j].x * xr[j].x;
            x2[j].y = xr[j].y * xr[j].y;
            x2[j].z = xr[j].z * xr[j].z;
            x2[j].w = xr[j].w * xr[j].w;
        }
        #pragma unroll
        for (int m = 0; m < 8; m++) {
            float a = acc[m];
            #pragma unroll
            for (int j = 0; j < 8; j++) {
                float4 iv4 = siv4[m * 16 + c * 8 + j];
                float4 b4  = sbiv4[m * 16 + c * 8 + j];
                a = fmaf(x2[j].x, iv4.x, a); a = fmaf(xr[j].x, b4.x, a);
                a = fmaf(x2[j].y, iv4.y, a); a = fmaf(xr[j].y, b4.y, a);
                a = fmaf(x2[j].z, iv4.z, a); a = fmaf(xr[j].z, b4.z, a);
                a = fmaf(x2[j].w, iv4.w, a); a = fmaf(xr[j].w, b4.w, a);
            }
            acc[m] = a;
        }
    }

    // emission[t,s] = logsumexp_m(-0.5*acc[m] + off[s,m])
    float comp[8];
    float mx = -INFINITY;
    #pragma unroll
    for (int m = 0; m < 8; m++) {
        comp[m] = -0.5f * acc[m] + soff[m];
        mx = fmaxf(mx, comp[m]);
    }
    float sum = 0.f;
    #pragma unroll
    for (int m = 0; m < 8; m++) sum += expf(comp[m] - mx);
    float em = mx + logf(sum);

    // block-reduce sum of em over 256 threads (fixed order -> deterministic)
    float v = em;
    #pragma unroll
    for (int o = 32; o > 0; o >>= 1) v += __shfl_down(v, o, 64);
    int wv = tid >> 6, ln = tid & 63;
    if (ln == 0) red[wv] = v;
    __syncthreads();
    if (tid == 0) part[blockIdx.x] = red[0] + red[1] + red[2] + red[3];
}

// ---------------- final: alpha_last and logsumexp over S --------------------
__global__ void final_kernel(const float* __restrict__ part,
                             const float* __restrict__ base,
                             float* __restrict__ out) {
    __shared__ float alpha[128];
    int s = threadIdx.x;                  // 128 threads
    float v = base[s];
    #pragma unroll
    for (int tb = 0; tb < 8; tb++) v += part[s * 8 + tb];
    alpha[s] = v;
    __syncthreads();
    if (s == 0) {
        float mx = -INFINITY;
        for (int j = 0; j < 128; j++) mx = fmaxf(mx, alpha[j]);
        float sum = 0.f;
        for (int j = 0; j < 128; j++) sum += expf(alpha[j] - mx);
        out[0] = mx + logf(sum);
    }
}

extern "C" void kernel_launch(void* const* d_in, const int* in_sizes, int n_in,
                              void* d_out, int out_size, void* d_ws, size_t ws_size,
                              hipStream_t stream) {
    const float* X      = (const float*)d_in[0];
    const float* pi_l   = (const float*)d_in[1];
    const float* trans  = (const float*)d_in[2];
    const float* weight = (const float*)d_in[3];
    const float* means  = (const float*)d_in[4];
    const float* lvars  = (const float*)d_in[5];
    float* out = (float*)d_out;

    float* ws_off  = (float*)d_ws;          // 1024
    float* ws_base = ws_off + 1024;         // 128
    float* ws_part = ws_base + 128;         // 1024

    prep_sm_kernel<<<256, 256, 0, stream>>>(lvars, means, ws_off);
    prep_s_kernel<<<1, 128, 0, stream>>>(pi_l, trans, weight, ws_off, ws_base);
    emis_kernel<<<S_N * TBLK, 256, 0, stream>>>(X, means, lvars, ws_off, ws_part);
    final_kernel<<<1, 128, 0, stream>>>(ws_part, ws_base, out);
}

// Round 2
// 30.003 us; speedup vs baseline: 2.0295x; 2.0295x over previous
//
#include <hip/hip_runtime.h>
#include <math.h>

#define LOG2PI 1.8378770664093453f

// ws layout (floats): iv[65536] | biv[65536] | off[1024] | base[128] | part[512]

// ---- prep over (s,m): iv, biv arrays + folded const term -------------------
__global__ void prep_sm_kernel(const float* __restrict__ log_vars,
                               const float* __restrict__ means,
                               float* __restrict__ iv_g,
                               float* __restrict__ biv_g,
                               float* __restrict__ off) {
    int wave = threadIdx.x >> 6;          // 4 waves/block
    int lane = threadIdx.x & 63;          // = d
    int sm = blockIdx.x * 4 + wave;       // 0..1023
    float lv = log_vars[sm * 64 + lane];
    float mu = means[sm * 64 + lane];
    float iv = expf(-lv);
    iv_g[sm * 64 + lane]  = iv;
    biv_g[sm * 64 + lane] = -2.0f * mu * iv;
    float a = lv;
    float b = mu * mu * iv;
    #pragma unroll
    for (int o = 32; o > 0; o >>= 1) {
        a += __shfl_down(a, o, 64);
        b += __shfl_down(b, o, 64);
    }
    if (lane == 0)
        off[sm] = -0.5f * (a + 64.0f * LOG2PI) - 0.5f * b;
}

// ---- prep over s: C[s] (wave-parallel) + weight log-softmax ----------------
__global__ void prep_s2_kernel(const float* __restrict__ trans_logits,
                               const float* __restrict__ weight_logits,
                               float* __restrict__ off,     // [S*8] +=
                               float* __restrict__ base) {  // [S] = 2047*C
    int wv = threadIdx.x >> 6, ln = threadIdx.x & 63;
    int s = blockIdx.x * 4 + wv;          // 32 blocks * 4 waves = 128
    const float* tr = trans_logits + s * 128;
    float v0 = tr[ln], v1 = tr[ln + 64];
    float m = fmaxf(v0, v1);
    #pragma unroll
    for (int o = 32; o > 0; o >>= 1) m = fmaxf(m, __shfl_xor(m, o, 64));
    float sum = expf(v0 - m) + expf(v1 - m);
    #pragma unroll
    for (int o = 32; o > 0; o >>= 1) sum += __shfl_xor(sum, o, 64);
    float L = m + logf(sum);
    float C = (m - L) + logf(sum);        // ~0, faithful to reference shape
    if (ln == 0) base[s] = 2047.0f * C;

    if (ln < 8) {                         // M=8 log-softmax, lanes 0..7
        float w = weight_logits[s * 8 + ln];
        float wm = w;
        #pragma unroll
        for (int o = 1; o < 8; o <<= 1) wm = fmaxf(wm, __shfl_xor(wm, o, 64));
        float we = expf(w - wm);
        float wsum = we;
        #pragma unroll
        for (int o = 1; o < 8; o <<= 1) wsum += __shfl_xor(wsum, o, 64);
        off[s * 8 + ln] += w - (wm + logf(wsum));
    }
}

// ---- main: emission log-probs, 2 t per thread ------------------------------
__global__ __launch_bounds__(256) void emis_kernel(
    const float* __restrict__ X,
    const float* __restrict__ iv_g,
    const float* __restrict__ biv_g,
    const float* __restrict__ off,
    float* __restrict__ part) {            // [S*4]
    __shared__ __align__(16) float siv[512];
    __shared__ __align__(16) float sbiv[512];
    __shared__ float soff[8];
    __shared__ float red[4];

    int s  = blockIdx.x >> 2;
    int tb = blockIdx.x & 3;
    int tid = threadIdx.x;

    {   // stage params: 128 float4 each array
        const float4* ivg4 = (const float4*)(iv_g + s * 512);
        const float4* bvg4 = (const float4*)(biv_g + s * 512);
        if (tid < 128) ((float4*)siv)[tid] = ivg4[tid];
        else           ((float4*)sbiv)[tid - 128] = bvg4[tid - 128];
    }
    if (tid < 8) soff[tid] = off[s * 8 + tid];
    __syncthreads();

    int t0 = tb * 512 + tid;               // t1 = t0 + 256
    const float4* Xv0 = (const float4*)(X + (size_t)t0 * 64);
    const float4* Xv1 = (const float4*)(X + (size_t)(t0 + 256) * 64);
    float4 x0[16], x1[16];
    #pragma unroll
    for (int j = 0; j < 16; j++) { x0[j] = Xv0[j]; x1[j] = Xv1[j]; }

    const float4* siv4  = (const float4*)siv;
    const float4* sbiv4 = (const float4*)sbiv;
    float acc0[8], acc1[8];

    #pragma unroll
    for (int m = 0; m < 8; m++) {
        float a0 = 0.f, a1 = 0.f;
        #pragma unroll
        for (int j = 0; j < 16; j++) {
            float4 iv4 = siv4[m * 16 + j];
            float4 b4  = sbiv4[m * 16 + j];
            float t;
            t = fmaf(x0[j].x, iv4.x, b4.x); a0 = fmaf(x0[j].x, t, a0);
            t = fmaf(x0[j].y, iv4.y, b4.y); a0 = fmaf(x0[j].y, t, a0);
            t = fmaf(x0[j].z, iv4.z, b4.z); a0 = fmaf(x0[j].z, t, a0);
            t = fmaf(x0[j].w, iv4.w, b4.w); a0 = fmaf(x0[j].w, t, a0);
            t = fmaf(x1[j].x, iv4.x, b4.x); a1 = fmaf(x1[j].x, t, a1);
            t = fmaf(x1[j].y, iv4.y, b4.y); a1 = fmaf(x1[j].y, t, a1);
            t = fmaf(x1[j].z, iv4.z, b4.z); a1 = fmaf(x1[j].z, t, a1);
            t = fmaf(x1[j].w, iv4.w, b4.w); a1 = fmaf(x1[j].w, t, a1);
        }
        acc0[m] = a0; acc1[m] = a1;
    }

    // em(t) = logsumexp_m(-0.5*acc[m] + off[s,m]); v = em(t0)+em(t1)
    float mx0 = -INFINITY, mx1 = -INFINITY;
    float c0[8], c1[8];
    #pragma unroll
    for (int m = 0; m < 8; m++) {
        c0[m] = fmaf(-0.5f, acc0[m], soff[m]); mx0 = fmaxf(mx0, c0[m]);
        c1[m] = fmaf(-0.5f, acc1[m], soff[m]); mx1 = fmaxf(mx1, c1[m]);
    }
    float s0 = 0.f, s1 = 0.f;
    #pragma unroll
    for (int m = 0; m < 8; m++) { s0 += expf(c0[m] - mx0); s1 += expf(c1[m] - mx1); }
    float v = (mx0 + logf(s0)) + (mx1 + logf(s1));

    // block reduce (fixed order)
    #pragma unroll
    for (int o = 32; o > 0; o >>= 1) v += __shfl_down(v, o, 64);
    int wv = tid >> 6, ln = tid & 63;
    if (ln == 0) red[wv] = v;
    __syncthreads();
    if (tid == 0) part[blockIdx.x] = red[0] + red[1] + red[2] + red[3];
}

// ---- final: log_pi lse + alpha + lse over S (parallel) ---------------------
__global__ void final_kernel(const float* __restrict__ part,
                             const float* __restrict__ base,
                             const float* __restrict__ pi_logits,
                             float* __restrict__ out) {
    __shared__ float smx[2], ssum[2], amx[2], asum[2];
    int tid = threadIdx.x;                // 128 threads, 2 waves
    int wv = tid >> 6, ln = tid & 63;

    float p = pi_logits[tid];
    float mx = p;
    #pragma unroll
    for (int o = 32; o > 0; o >>= 1) mx = fmaxf(mx, __shfl_xor(mx, o, 64));
    if (ln == 0) smx[wv] = mx;
    __syncthreads();
    float gmx = fmaxf(smx[0], smx[1]);
    float e = expf(p - gmx);
    #pragma unroll
    for (int o = 32; o > 0; o >>= 1) e += __shfl_xor(e, o, 64);
    if (ln == 0) ssum[wv] = e;
    __syncthreads();
    float lsepi = gmx + logf(ssum[0] + ssum[1]);

    float v = base[tid];
    #pragma unroll
    for (int tb = 0; tb < 4; tb++) v += part[tid * 4 + tb];
    float alpha = (p - lsepi) + v;

    float m2 = alpha;
    #pragma unroll
    for (int o = 32; o > 0; o >>= 1) m2 = fmaxf(m2, __shfl_xor(m2, o, 64));
    if (ln == 0) amx[wv] = m2;
    __syncthreads();
    float g2 = fmaxf(amx[0], amx[1]);
    float e2 = expf(alpha - g2);
    #pragma unroll
    for (int o = 32; o > 0; o >>= 1) e2 += __shfl_xor(e2, o, 64);
    if (ln == 0) asum[wv] = e2;
    __syncthreads();
    if (tid == 0) out[0] = g2 + logf(asum[0] + asum[1]);
}

extern "C" void kernel_launch(void* const* d_in, const int* in_sizes, int n_in,
                              void* d_out, int out_size, void* d_ws, size_t ws_size,
                              hipStream_t stream) {
    const float* X      = (const float*)d_in[0];
    const float* pi_l   = (const float*)d_in[1];
    const float* trans  = (const float*)d_in[2];
    const float* weight = (const float*)d_in[3];
    const float* means  = (const float*)d_in[4];
    const float* lvars  = (const float*)d_in[5];
    float* out = (float*)d_out;

    float* ws_iv   = (float*)d_ws;          // 65536
    float* ws_biv  = ws_iv + 65536;         // 65536
    float* ws_off  = ws_biv + 65536;        // 1024
    float* ws_base = ws_off + 1024;         // 128
    float* ws_part = ws_base + 128;         // 512

    prep_sm_kernel<<<256, 256, 0, stream>>>(lvars, means, ws_iv, ws_biv, ws_off);
    prep_s2_kernel<<<32, 256, 0, stream>>>(trans, weight, ws_off, ws_base);
    emis_kernel<<<512, 256, 0, stream>>>(X, ws_iv, ws_biv, ws_off, ws_part);
    final_kernel<<<1, 128, 0, stream>>>(ws_part, ws_base, pi_l, out);
}

// Round 3
// 25.869 us; speedup vs baseline: 2.3539x; 1.1598x over previous
//
#include <hip/hip_runtime.h>
#include <math.h>

#define LOG2PI 1.8378770664093453f

// ws layout (floats): part[256] | base[128]

// ---- fused: per-state prep + emission + per-block t-sum --------------------
// grid = 256 blocks (s = bid>>1, tb = bid&1), 256 threads. 1 block/CU.
__global__ __launch_bounds__(256) void emis_fused_kernel(
    const float* __restrict__ X,
    const float* __restrict__ means,
    const float* __restrict__ log_vars,
    const float* __restrict__ weight_logits,
    const float* __restrict__ trans_logits,
    float* __restrict__ part,              // [256]
    float* __restrict__ base) {            // [128]
    __shared__ __align__(16) float siv[512];   // iv[m][d]
    __shared__ __align__(16) float sbiv[512];  // -2*mu*iv
    __shared__ float soff[8];
    __shared__ float red[4];

    int s  = blockIdx.x >> 1;
    int tb = blockIdx.x & 1;
    int tid = threadIdx.x;
    int wv = tid >> 6, ln = tid & 63;

    // ---- stage params + per-m const folding (wave wv handles m=wv, wv+4) ---
    #pragma unroll
    for (int p = 0; p < 2; p++) {
        int i = tid + p * 256;             // m = wv + 4p, d = ln
        float lv = log_vars[s * 512 + i];
        float mu = means[s * 512 + i];
        float iv = expf(-lv);
        siv[i]  = iv;
        sbiv[i] = -2.0f * mu * iv;
        float a = lv;
        float b = mu * mu * iv;
        #pragma unroll
        for (int o = 32; o > 0; o >>= 1) {
            a += __shfl_down(a, o, 64);
            b += __shfl_down(b, o, 64);
        }
        if (ln == 0)
            soff[wv + 4 * p] = -0.5f * (a + 64.0f * LOG2PI) - 0.5f * b;
    }
    __syncthreads();

    // wave 0: weight log-softmax folded into soff (lanes 0..7)
    if (wv == 0 && ln < 8) {
        float w = weight_logits[s * 8 + ln];
        float wm = w;
        #pragma unroll
        for (int o = 1; o < 8; o <<= 1) wm = fmaxf(wm, __shfl_xor(wm, o, 64));
        float we = expf(w - wm);
        float wsum = we;
        #pragma unroll
        for (int o = 1; o < 8; o <<= 1) wsum += __shfl_xor(wsum, o, 64);
        soff[ln] += w - (wm + logf(wsum));
    }
    // wave 1 of tb==0 blocks: base[s] = 2047 * logsumexp(log_A row)
    if (wv == 1 && tb == 0) {
        const float* tr = trans_logits + s * 128;
        float v0 = tr[ln], v1 = tr[ln + 64];
        float m = fmaxf(v0, v1);
        #pragma unroll
        for (int o = 32; o > 0; o >>= 1) m = fmaxf(m, __shfl_xor(m, o, 64));
        float sum = expf(v0 - m) + expf(v1 - m);
        #pragma unroll
        for (int o = 32; o > 0; o >>= 1) sum += __shfl_xor(sum, o, 64);
        float L = m + logf(sum);
        float C = (m - L) + logf(sum);
        if (ln == 0) base[s] = 2047.0f * C;
    }
    __syncthreads();

    // ---- main: 4 t per thread, d chunked by 32 -----------------------------
    int t0 = tb * 1024 + tid;              // rows t0 + r*256, r=0..3
    const float4* siv4  = (const float4*)siv;
    const float4* sbiv4 = (const float4*)sbiv;

    float acc[4][8];
    #pragma unroll
    for (int r = 0; r < 4; r++)
        #pragma unroll
        for (int m = 0; m < 8; m++) acc[r][m] = 0.f;

    #pragma unroll
    for (int c = 0; c < 2; c++) {
        float4 x[4][8];
        #pragma unroll
        for (int r = 0; r < 4; r++) {
            const float4* Xv = (const float4*)(X + (size_t)(t0 + r * 256) * 64);
            #pragma unroll
            for (int j = 0; j < 8; j++) x[r][j] = Xv[c * 8 + j];
        }
        #pragma unroll
        for (int m = 0; m < 8; m++) {
            #pragma unroll
            for (int j = 0; j < 8; j++) {
                float4 iv4 = siv4[m * 16 + c * 8 + j];
                float4 b4  = sbiv4[m * 16 + c * 8 + j];
                #pragma unroll
                for (int r = 0; r < 4; r++) {
                    float t;
                    t = fmaf(x[r][j].x, iv4.x, b4.x); acc[r][m] = fmaf(x[r][j].x, t, acc[r][m]);
                    t = fmaf(x[r][j].y, iv4.y, b4.y); acc[r][m] = fmaf(x[r][j].y, t, acc[r][m]);
                    t = fmaf(x[r][j].z, iv4.z, b4.z); acc[r][m] = fmaf(x[r][j].z, t, acc[r][m]);
                    t = fmaf(x[r][j].w, iv4.w, b4.w); acc[r][m] = fmaf(x[r][j].w, t, acc[r][m]);
                }
            }
        }
    }

    // em(t) = logsumexp_m(-0.5*acc + soff); v = sum over this thread's 4 t's
    float so[8];
    #pragma unroll
    for (int m = 0; m < 8; m++) so[m] = soff[m];

    float v = 0.f;
    #pragma unroll
    for (int r = 0; r < 4; r++) {
        float cmp[8], mx = -INFINITY;
        #pragma unroll
        for (int m = 0; m < 8; m++) {
            cmp[m] = fmaf(-0.5f, acc[r][m], so[m]);
            mx = fmaxf(mx, cmp[m]);
        }
        float sum = 0.f;
        #pragma unroll
        for (int m = 0; m < 8; m++) sum += __expf(cmp[m] - mx);
        v += mx + __logf(sum);
    }

    // block reduce (fixed order -> deterministic)
    #pragma unroll
    for (int o = 32; o > 0; o >>= 1) v += __shfl_down(v, o, 64);
    if (ln == 0) red[wv] = v;
    __syncthreads();
    if (tid == 0) part[blockIdx.x] = red[0] + red[1] + red[2] + red[3];
}

// ---- final: log_pi lse + alpha + lse over S (parallel) ---------------------
__global__ void final_kernel(const float* __restrict__ part,
                             const float* __restrict__ base,
                             const float* __restrict__ pi_logits,
                             float* __restrict__ out) {
    __shared__ float smx[2], ssum[2], amx[2], asum[2];
    int tid = threadIdx.x;                // 128 threads, 2 waves
    int wv = tid >> 6, ln = tid & 63;

    float p = pi_logits[tid];
    float mx = p;
    #pragma unroll
    for (int o = 32; o > 0; o >>= 1) mx = fmaxf(mx, __shfl_xor(mx, o, 64));
    if (ln == 0) smx[wv] = mx;
    __syncthreads();
    float gmx = fmaxf(smx[0], smx[1]);
    float e = expf(p - gmx);
    #pragma unroll
    for (int o = 32; o > 0; o >>= 1) e += __shfl_xor(e, o, 64);
    if (ln == 0) ssum[wv] = e;
    __syncthreads();
    float lsepi = gmx + logf(ssum[0] + ssum[1]);

    float alpha = (p - lsepi) + base[tid] + part[tid * 2] + part[tid * 2 + 1];

    float m2 = alpha;
    #pragma unroll
    for (int o = 32; o > 0; o >>= 1) m2 = fmaxf(m2, __shfl_xor(m2, o, 64));
    if (ln == 0) amx[wv] = m2;
    __syncthreads();
    float g2 = fmaxf(amx[0], amx[1]);
    float e2 = expf(alpha - g2);
    #pragma unroll
    for (int o = 32; o > 0; o >>= 1) e2 += __shfl_xor(e2, o, 64);
    if (ln == 0) asum[wv] = e2;
    __syncthreads();
    if (tid == 0) out[0] = g2 + logf(asum[0] + asum[1]);
}

extern "C" void kernel_launch(void* const* d_in, const int* in_sizes, int n_in,
                              void* d_out, int out_size, void* d_ws, size_t ws_size,
                              hipStream_t stream) {
    const float* X      = (const float*)d_in[0];
    const float* pi_l   = (const float*)d_in[1];
    const float* trans  = (const float*)d_in[2];
    const float* weight = (const float*)d_in[3];
    const float* means  = (const float*)d_in[4];
    const float* lvars  = (const float*)d_in[5];
    float* out = (float*)d_out;

    float* ws_part = (float*)d_ws;          // 256
    float* ws_base = ws_part + 256;         // 128

    emis_fused_kernel<<<256, 256, 0, stream>>>(X, means, lvars, weight, trans,
                                               ws_part, ws_base);
    final_kernel<<<1, 128, 0, stream>>>(ws_part, ws_base, pi_l, out);
}